// Round 1
// baseline (248.529 us; speedup 1.0000x reference)
//
#include <hip/hip_runtime.h>

#define G    128
#define GGG  (G * G * G)
#define C    128
#define KK   27

// ---------------------------------------------------------------------------
// Kernel 1: init grid to -1
// ---------------------------------------------------------------------------
__global__ void init_grid_kernel(int* __restrict__ grid) {
    int i = blockIdx.x * blockDim.x + threadIdx.x;
    if (i < GGG) grid[i] = -1;
}

// ---------------------------------------------------------------------------
// Kernel 2: scatter input point indices; duplicates take max index
// ---------------------------------------------------------------------------
__global__ void scatter_kernel(const int* __restrict__ pos,
                               int* __restrict__ grid, int n) {
    int i = blockIdx.x * blockDim.x + threadIdx.x;
    if (i >= n) return;
    int x = pos[3 * i], y = pos[3 * i + 1], z = pos[3 * i + 2];
    atomicMax(&grid[(x * G + y) * G + z], i);
}

// ---------------------------------------------------------------------------
// Kernel 3: one 128-thread block per output row.
//   threads 0..26 do the 27 grid lookups -> LDS
//   per active tap m: stage feature row (512B) -> LDS, then each thread
//   (one output channel c) dots it with W[26-m][:, c].
// ---------------------------------------------------------------------------
__global__ __launch_bounds__(128) void gather_mm_kernel(
    const float* __restrict__ features, const float* __restrict__ W,
    const int* __restrict__ out_pos, const int* __restrict__ grid,
    float* __restrict__ out, int n_out)
{
    int row = blockIdx.x;
    if (row >= n_out) return;
    int c = threadIdx.x;

    __shared__ int   nb_idx[KK];
    __shared__ float feat_s[C];

    int px = out_pos[3 * row], py = out_pos[3 * row + 1], pz = out_pos[3 * row + 2];

    if (c < KK) {
        int i = c / 9, j = (c % 9) / 3, k = c % 3;
        int x = px + i - 1, y = py + j - 1, z = pz + k - 1;
        int idx = -1;
        if ((unsigned)x < G && (unsigned)y < G && (unsigned)z < G)
            idx = grid[(x * G + y) * G + z];
        nb_idx[c] = idx;
    }
    __syncthreads();

    float acc = 0.f;
    for (int m = 0; m < KK; ++m) {
        int idx = nb_idx[m];          // block-uniform -> no divergence hazard
        if (idx < 0) continue;

        __syncthreads();              // previous iteration finished with feat_s
        feat_s[c] = features[idx * C + c];
        __syncthreads();

        const float* __restrict__ Wk = W + (KK - 1 - m) * C * C + c;
        float a = 0.f;
#pragma unroll
        for (int ci = 0; ci < C; ++ci)
            a += feat_s[ci] * Wk[ci * C];
        acc += a;
    }
    out[row * C + c] = acc;
}

// ---------------------------------------------------------------------------
extern "C" void kernel_launch(void* const* d_in, const int* in_sizes, int n_in,
                              void* d_out, int out_size, void* d_ws, size_t ws_size,
                              hipStream_t stream) {
    const float* features = (const float*)d_in[0];
    const float* W        = (const float*)d_in[1];
    const int*   inp_pos  = (const int*)d_in[2];
    const int*   out_pos  = (const int*)d_in[3];
    float*       out      = (float*)d_out;

    int n_in_pts  = in_sizes[2] / 3;   // 50000
    int n_out_pts = out_size / C;      // 100000
    int* grid     = (int*)d_ws;        // 8 MiB for the voxel grid

    hipLaunchKernelGGL(init_grid_kernel, dim3((GGG + 255) / 256), dim3(256), 0, stream,
                       grid);
    hipLaunchKernelGGL(scatter_kernel, dim3((n_in_pts + 255) / 256), dim3(256), 0, stream,
                       inp_pos, grid, n_in_pts);
    hipLaunchKernelGGL(gather_mm_kernel, dim3(n_out_pts), dim3(128), 0, stream,
                       features, W, out_pos, grid, out, n_out_pts);
}